// Round 1
// baseline (1292.767 us; speedup 1.0000x reference)
//
#include <hip/hip_runtime.h>
#include <cfloat>

#define BB 2
#define CC 64
#define NN 8192
#define OO 64
#define KK 20
#define MS 8          // m-splits in kernel B
#define CHUNK 1024    // m-range per block in kernel B
#define PM 128        // points staged per LDS chunk

// ws layout (in float units)
#define XT_OFF  ((size_t)0)                          // B*N*64
#define SQ_OFF  (XT_OFF + (size_t)BB*NN*64)          // B*N
#define Y1_OFF  (SQ_OFF + (size_t)BB*NN)             // B*N*64
#define Y2_OFF  (Y1_OFF + (size_t)BB*NN*64)          // B*N*64
#define CD_OFF  (Y2_OFF + (size_t)BB*NN*64)          // B*N*MS*K (float)
#define CI_OFF  (CD_OFF + (size_t)BB*NN*MS*KK)       // B*N*MS*K (int)
#define IX_OFF  (CI_OFF + (size_t)BB*NN*MS*KK)       // B*N*K (int)
#define HX_OFF  (IX_OFF + (size_t)BB*NN*KK)          // B*N*64
#define HN_OFF  (HX_OFF + (size_t)BB*NN*64)          // B*N*64
#define ST_OFF  (HN_OFF + (size_t)BB*NN*64)          // 128

// ---------------- kernel A: transpose + sq + y1/y2 projections ----------------
__global__ void kA(const float* __restrict__ x, const float* __restrict__ W,
                   float* __restrict__ ws) {
    __shared__ float w1[64 * 64];
    __shared__ float w2[64 * 64];
    int b = blockIdx.y;
    int n = blockIdx.x * 64 + threadIdx.x;

    for (int i = threadIdx.x; i < 4096; i += 64) {
        int o = i >> 6, c = i & 63;
        float a  = W[o * 128 + c];
        float b2 = W[o * 128 + 64 + c];
        w1[i] = a;
        w2[i] = b2 - a;
    }
    // zero global stats accumulators (runs before kC1 in stream order)
    if (blockIdx.x == 0 && b == 0) {
        ws[ST_OFF + threadIdx.x] = 0.f;
        ws[ST_OFF + 64 + threadIdx.x] = 0.f;
    }
    __syncthreads();

    float xc[64];
    float sq = 0.f;
#pragma unroll
    for (int c = 0; c < 64; ++c) {
        float v = x[((size_t)b * 64 + c) * NN + n];   // coalesced across lanes
        xc[c] = v;
        sq += v * v;
    }
    ws[SQ_OFF + (size_t)b * NN + n] = sq;

    float4* xtr = (float4*)&ws[XT_OFF + ((size_t)b * NN + n) * 64];
#pragma unroll
    for (int c4 = 0; c4 < 16; ++c4)
        xtr[c4] = make_float4(xc[4*c4], xc[4*c4+1], xc[4*c4+2], xc[4*c4+3]);

    float* y1r = &ws[Y1_OFF + ((size_t)b * NN + n) * 64];
    float* y2r = &ws[Y2_OFF + ((size_t)b * NN + n) * 64];
#pragma unroll 2
    for (int o = 0; o < 64; ++o) {
        float a1 = 0.f, a2 = 0.f;
#pragma unroll
        for (int c = 0; c < 64; ++c) {
            a1 += w1[o * 64 + c] * xc[c];
            a2 += w2[o * 64 + c] * xc[c];
        }
        y1r[o] = a1;
        y2r[o] = a2;
    }
}

// ---------------- kernel B: distances + per-thread top-K (per m-chunk) ----------------
__global__ void kB(const float* __restrict__ xt, const float* __restrict__ sq,
                   float* __restrict__ candd, int* __restrict__ candi) {
    __shared__ __align__(16) float lp[PM * 64];
    __shared__ float lsq[PM];
    int b = blockIdx.z;
    int q = blockIdx.x * 256 + threadIdx.x;
    int mbase0 = blockIdx.y * CHUNK;

    float4 qv[16];
    const float4* qr = (const float4*)&xt[((size_t)b * NN + q) * 64];
#pragma unroll
    for (int i = 0; i < 16; ++i) qv[i] = qr[i];

    float dk[KK];
    int   ik[KK];
#pragma unroll
    for (int i = 0; i < KK; ++i) { dk[i] = FLT_MAX; ik[i] = 0; }

    for (int mc = 0; mc < CHUNK; mc += PM) {
        int mb = mbase0 + mc;
        __syncthreads();
        const float4* src = (const float4*)&xt[((size_t)b * NN + mb) * 64];
        float4* dst = (float4*)lp;
        for (int i = threadIdx.x; i < PM * 16; i += 256) dst[i] = src[i];
        for (int i = threadIdx.x; i < PM; i += 256) lsq[i] = sq[(size_t)b * NN + mb + i];
        __syncthreads();

#pragma unroll 2
        for (int p = 0; p < PM; ++p) {
            const float4* pr = (const float4*)&lp[p * 64];
            float a0 = 0.f, a1 = 0.f, a2 = 0.f, a3 = 0.f;
#pragma unroll
            for (int c4 = 0; c4 < 16; ++c4) {
                float4 pv = pr[c4];   // broadcast ds_read_b128
                a0 += qv[c4].x * pv.x;
                a1 += qv[c4].y * pv.y;
                a2 += qv[c4].z * pv.z;
                a3 += qv[c4].w * pv.w;
            }
            float dot = (a0 + a1) + (a2 + a3);
            float d = lsq[p] - 2.f * dot;   // sq[q] dropped: constant per query
            if (d < dk[KK - 1]) {           // strict <: lower index wins ties (matches top_k)
                dk[KK - 1] = d;
                ik[KK - 1] = mb + p;
#pragma unroll
                for (int i = KK - 1; i > 0; --i) {
                    float x0 = dk[i - 1], x1 = dk[i];
                    bool sw = x1 < x0;
                    dk[i - 1] = sw ? x1 : x0;
                    dk[i]     = sw ? x0 : x1;
                    int y0 = ik[i - 1], y1i = ik[i];
                    ik[i - 1] = sw ? y1i : y0;
                    ik[i]     = sw ? y0 : y1i;
                }
            }
        }
    }

    size_t base = (((size_t)b * NN + q) * MS + blockIdx.y) * KK;
#pragma unroll
    for (int i = 0; i < KK; ++i) {
        candd[base + i] = dk[i];
        candi[base + i] = ik[i];
    }
}

// ---------------- kernel M: merge MS candidate lists per query ----------------
__global__ void kM(const float* __restrict__ candd, const int* __restrict__ candi,
                   int* __restrict__ idxK) {
    int g = blockIdx.x * 256 + threadIdx.x;   // 0 .. B*N-1
    const float* cd = &candd[(size_t)g * MS * KK];
    const int*   ci = &candi[(size_t)g * MS * KK];
    float dk[KK];
    int   ik[KK];
#pragma unroll
    for (int i = 0; i < KK; ++i) { dk[i] = cd[i]; ik[i] = ci[i]; }   // chunk 0, sorted
    for (int t = KK; t < MS * KK; ++t) {
        float d = cd[t];
        if (d < dk[KK - 1]) {   // chunks scanned in ascending-m order; strict < keeps earlier
            dk[KK - 1] = d;
            ik[KK - 1] = ci[t];
#pragma unroll
            for (int i = KK - 1; i > 0; --i) {
                float x0 = dk[i - 1], x1 = dk[i];
                bool sw = x1 < x0;
                dk[i - 1] = sw ? x1 : x0;
                dk[i]     = sw ? x0 : x1;
                int y0 = ik[i - 1], y1i = ik[i];
                ik[i - 1] = sw ? y1i : y0;
                ik[i]     = sw ? y0 : y1i;
            }
        }
    }
    int* outp = &idxK[(size_t)g * KK];
#pragma unroll
    for (int i = 0; i < KK; ++i) outp[i] = ik[i];
}

// ---------------- kernel C1: gather + stats + hmax/hmin ----------------
__global__ void kC1(const float* __restrict__ y1, const float* __restrict__ y2,
                    const int* __restrict__ idxK, float* __restrict__ hmax,
                    float* __restrict__ hmin, float* __restrict__ stats) {
    __shared__ int li[4 * KK];
    __shared__ float red[256];
    int b = blockIdx.y;
    int o = threadIdx.x & 63;
    int nn = threadIdx.x >> 6;
    int nbase = blockIdx.x * 128;
    float s = 0.f, ss = 0.f;

    for (int gidx = 0; gidx < 32; ++gidx) {
        int n0 = nbase + gidx * 4;
        __syncthreads();
        if (threadIdx.x < 4 * KK)
            li[threadIdx.x] = idxK[((size_t)b * NN + n0) * KK + threadIdx.x];
        __syncthreads();
        int n = n0 + nn;
        float y2v = y2[((size_t)b * NN + n) * 64 + o];
        float hm = -FLT_MAX, hn = FLT_MAX;
        for (int k = 0; k < KK; ++k) {
            int j = li[nn * KK + k];   // wave-uniform within a wave (nn fixed per wave)
            float h = y1[((size_t)b * NN + j) * 64 + o] + y2v;   // coalesced 256B row, L2-hot
            s += h;
            ss += h * h;
            hm = fmaxf(hm, h);
            hn = fminf(hn, h);
        }
        hmax[((size_t)b * NN + n) * 64 + o] = hm;
        hmin[((size_t)b * NN + n) * 64 + o] = hn;
    }

    __syncthreads();
    red[threadIdx.x] = s;
    __syncthreads();
    if (threadIdx.x < 64) {
        float v = red[o] + red[64 + o] + red[128 + o] + red[192 + o];
        atomicAdd(&stats[o], v);
    }
    __syncthreads();
    red[threadIdx.x] = ss;
    __syncthreads();
    if (threadIdx.x < 64) {
        float v = red[o] + red[64 + o] + red[128 + o] + red[192 + o];
        atomicAdd(&stats[64 + o], v);
    }
}

// ---------------- kernel C3: finalize BN + leaky + max-over-k ----------------
__global__ void kC3(const float* __restrict__ hmax, const float* __restrict__ hmin,
                    const float* __restrict__ stats, const float* __restrict__ gamma,
                    const float* __restrict__ beta, float* __restrict__ out) {
    int o = blockIdx.x;
    int b = blockIdx.y;
    const float cnt = (float)BB * NN * KK;
    float mean = stats[o] / cnt;
    float var = stats[64 + o] / cnt - mean * mean;
    float rs = rsqrtf(var + 1e-5f);
    float a = gamma[o] * rs;
    float b2 = beta[o] - a * mean;
    for (int n = threadIdx.x; n < NN; n += 256) {
        float hm = hmax[((size_t)b * NN + n) * 64 + o];
        float hn = hmin[((size_t)b * NN + n) * 64 + o];
        float hs = (a >= 0.f) ? hm : hn;   // affine monotone: pick max or min per sign
        float v = a * hs + b2;
        v = (v >= 0.f) ? v : 0.2f * v;
        out[((size_t)b * 64 + o) * NN + n] = v;   // coalesced
    }
}

extern "C" void kernel_launch(void* const* d_in, const int* in_sizes, int n_in,
                              void* d_out, int out_size, void* d_ws, size_t ws_size,
                              hipStream_t stream) {
    const float* x     = (const float*)d_in[0];
    const float* W     = (const float*)d_in[1];
    const float* gamma = (const float*)d_in[2];
    const float* beta  = (const float*)d_in[3];
    float* out = (float*)d_out;
    float* ws  = (float*)d_ws;

    float* xt    = ws + XT_OFF;
    float* sq    = ws + SQ_OFF;
    float* y1    = ws + Y1_OFF;
    float* y2    = ws + Y2_OFF;
    float* candd = ws + CD_OFF;
    int*   candi = (int*)(ws + CI_OFF);
    int*   idxK  = (int*)(ws + IX_OFF);
    float* hmax  = ws + HX_OFF;
    float* hmin  = ws + HN_OFF;
    float* stats = ws + ST_OFF;

    kA<<<dim3(NN / 64, BB), 64, 0, stream>>>(x, W, ws);
    kB<<<dim3(NN / 256, MS, BB), 256, 0, stream>>>(xt, sq, candd, candi);
    kM<<<dim3(BB * NN / 256), 256, 0, stream>>>(candd, candi, idxK);
    kC1<<<dim3(NN / 128, BB), 256, 0, stream>>>(y1, y2, idxK, hmax, hmin, stats);
    kC3<<<dim3(OO, BB), 256, 0, stream>>>(hmax, hmin, stats, gamma, beta, out);
}

// Round 2
// 1019.088 us; speedup vs baseline: 1.2686x; 1.2686x over previous
//
#include <hip/hip_runtime.h>
#include <cfloat>

#define BB 2
#define CC 64
#define NN 8192
#define OO 64
#define KK 20
#define MS 8          // m-splits in kernel B
#define CHUNK 1024    // m-range per block in kernel B
#define PM 64         // points staged per LDS chunk
#define CAP 16        // per-thread deferred candidate buffer depth

// ws layout (in float units)
#define XT_OFF  ((size_t)0)                          // B*N*64
#define SQ_OFF  (XT_OFF + (size_t)BB*NN*64)          // B*N
#define Y1_OFF  (SQ_OFF + (size_t)BB*NN)             // B*N*64
#define Y2_OFF  (Y1_OFF + (size_t)BB*NN*64)          // B*N*64
#define CD_OFF  (Y2_OFF + (size_t)BB*NN*64)          // B*N*MS*K (float)
#define CI_OFF  (CD_OFF + (size_t)BB*NN*MS*KK)       // B*N*MS*K (int)
#define IX_OFF  (CI_OFF + (size_t)BB*NN*MS*KK)       // B*N*K (int)
#define HX_OFF  (IX_OFF + (size_t)BB*NN*KK)          // B*N*64
#define HN_OFF  (HX_OFF + (size_t)BB*NN*64)          // B*N*64
#define ST_OFF  (HN_OFF + (size_t)BB*NN*64)          // 128

// ---------------- kernel A: transpose + sq + y1/y2 projections ----------------
__global__ void kA(const float* __restrict__ x, const float* __restrict__ W,
                   float* __restrict__ ws) {
    __shared__ float w1[64 * 64];
    __shared__ float w2[64 * 64];
    int b = blockIdx.y;
    int n = blockIdx.x * 64 + threadIdx.x;

    for (int i = threadIdx.x; i < 4096; i += 64) {
        int o = i >> 6, c = i & 63;
        float a  = W[o * 128 + c];
        float b2 = W[o * 128 + 64 + c];
        w1[i] = a;
        w2[i] = b2 - a;
    }
    // zero global stats accumulators (runs before kC1 in stream order)
    if (blockIdx.x == 0 && b == 0) {
        ws[ST_OFF + threadIdx.x] = 0.f;
        ws[ST_OFF + 64 + threadIdx.x] = 0.f;
    }
    __syncthreads();

    float xc[64];
    float sq = 0.f;
#pragma unroll
    for (int c = 0; c < 64; ++c) {
        float v = x[((size_t)b * 64 + c) * NN + n];   // coalesced across lanes
        xc[c] = v;
        sq += v * v;
    }
    ws[SQ_OFF + (size_t)b * NN + n] = sq;

    float4* xtr = (float4*)&ws[XT_OFF + ((size_t)b * NN + n) * 64];
#pragma unroll
    for (int c4 = 0; c4 < 16; ++c4)
        xtr[c4] = make_float4(xc[4*c4], xc[4*c4+1], xc[4*c4+2], xc[4*c4+3]);

    float* y1r = &ws[Y1_OFF + ((size_t)b * NN + n) * 64];
    float* y2r = &ws[Y2_OFF + ((size_t)b * NN + n) * 64];
#pragma unroll 2
    for (int o = 0; o < 64; ++o) {
        float a1 = 0.f, a2 = 0.f;
#pragma unroll
        for (int c = 0; c < 64; ++c) {
            a1 += w1[o * 64 + c] * xc[c];
            a2 += w2[o * 64 + c] * xc[c];
        }
        y1r[o] = a1;
        y2r[o] = a2;
    }
}

// ---------------- kernel B: distances + deferred per-thread top-K ----------------
__global__ void __launch_bounds__(256, 1)
kB(const float* __restrict__ xt, const float* __restrict__ sq,
   float* __restrict__ candd, int* __restrict__ candi) {
    __shared__ __align__(16) float lp[PM * 64];
    __shared__ float lsq[PM];
    __shared__ unsigned long long buf[CAP * 256];   // deferred (d,idx) per thread

    int b = blockIdx.z;
    int q = blockIdx.x * 256 + threadIdx.x;
    int mbase0 = blockIdx.y * CHUNK;

    float4 qv[16];
    const float4* qr = (const float4*)&xt[((size_t)b * NN + q) * 64];
#pragma unroll
    for (int i = 0; i < 16; ++i) qv[i] = qr[i];

    float dk[KK];
    int   ik[KK];
#pragma unroll
    for (int i = 0; i < KK; ++i) { dk[i] = FLT_MAX; ik[i] = 0; }
    int cnt = 0;

    // flush the deferred buffer into the sorted register top-20
    auto flushbuf = [&]() {
#pragma unroll 1
        for (int j = 0; j < CAP; ++j) {
            if (!__any(j < cnt)) break;
            unsigned long long v = buf[j * 256 + threadIdx.x];
            float d = __uint_as_float((unsigned)(v >> 32));
            int  id = (int)(unsigned)(v & 0xffffffffu);
            if (j < cnt && d < dk[KK - 1]) {
                dk[KK - 1] = d;
                ik[KK - 1] = id;
#pragma unroll
                for (int i = KK - 1; i > 0; --i) {
                    float x0 = dk[i - 1], x1 = dk[i];
                    bool sw = x1 < x0;          // strict <: lower index wins ties
                    dk[i - 1] = sw ? x1 : x0;
                    dk[i]     = sw ? x0 : x1;
                    int y0 = ik[i - 1], y1i = ik[i];
                    ik[i - 1] = sw ? y1i : y0;
                    ik[i]     = sw ? y0 : y1i;
                }
            }
        }
        cnt = 0;
    };

    for (int mc = 0; mc < CHUNK; mc += PM) {
        int mb = mbase0 + mc;
        __syncthreads();
        const float4* src = (const float4*)&xt[((size_t)b * NN + mb) * 64];
        float4* dst = (float4*)lp;
        for (int i = threadIdx.x; i < PM * 16; i += 256) dst[i] = src[i];
        if (threadIdx.x < PM) lsq[threadIdx.x] = sq[(size_t)b * NN + mb + threadIdx.x];
        __syncthreads();

#pragma unroll 1
        for (int p = 0; p < PM; ++p) {
            const float4* pr = (const float4*)&lp[p * 64];
            float a0 = 0.f, a1 = 0.f, a2 = 0.f, a3 = 0.f;
#pragma unroll
            for (int c4 = 0; c4 < 16; ++c4) {
                float4 pv = pr[c4];   // broadcast ds_read_b128 (lane-uniform addr)
                a0 += qv[c4].x * pv.x;
                a1 += qv[c4].y * pv.y;
                a2 += qv[c4].z * pv.z;
                a3 += qv[c4].w * pv.w;
            }
            float dot = (a0 + a1) + (a2 + a3);
            float d = lsq[p] - 2.f * dot;   // sq[q] dropped: constant per query
            if (d < dk[KK - 1]) {           // threshold from last flush: superset, exact at flush
                buf[cnt * 256 + threadIdx.x] =
                    ((unsigned long long)__float_as_uint(d) << 32) | (unsigned)(mb + p);
                cnt++;
            }
            if (__any(cnt >= CAP)) flushbuf();
        }
    }
    flushbuf();   // drain remainder

    size_t base = (((size_t)b * NN + q) * MS + blockIdx.y) * KK;
#pragma unroll
    for (int i = 0; i < KK; ++i) {
        candd[base + i] = dk[i];
        candi[base + i] = ik[i];
    }
}

// ---------------- kernel M: merge MS candidate lists per query ----------------
__global__ void kM(const float* __restrict__ candd, const int* __restrict__ candi,
                   int* __restrict__ idxK) {
    int g = blockIdx.x * 256 + threadIdx.x;   // 0 .. B*N-1
    const float* cd = &candd[(size_t)g * MS * KK];
    const int*   ci = &candi[(size_t)g * MS * KK];
    float dk[KK];
    int   ik[KK];
#pragma unroll
    for (int i = 0; i < KK; ++i) { dk[i] = cd[i]; ik[i] = ci[i]; }   // chunk 0, sorted
    for (int t = KK; t < MS * KK; ++t) {
        float d = cd[t];
        if (d < dk[KK - 1]) {   // chunks scanned in ascending-m order; strict < keeps earlier
            dk[KK - 1] = d;
            ik[KK - 1] = ci[t];
#pragma unroll
            for (int i = KK - 1; i > 0; --i) {
                float x0 = dk[i - 1], x1 = dk[i];
                bool sw = x1 < x0;
                dk[i - 1] = sw ? x1 : x0;
                dk[i]     = sw ? x0 : x1;
                int y0 = ik[i - 1], y1i = ik[i];
                ik[i - 1] = sw ? y1i : y0;
                ik[i]     = sw ? y0 : y1i;
            }
        }
    }
    int* outp = &idxK[(size_t)g * KK];
#pragma unroll
    for (int i = 0; i < KK; ++i) outp[i] = ik[i];
}

// ---------------- kernel C1: gather + stats + hmax/hmin ----------------
__global__ void kC1(const float* __restrict__ y1, const float* __restrict__ y2,
                    const int* __restrict__ idxK, float* __restrict__ hmax,
                    float* __restrict__ hmin, float* __restrict__ stats) {
    __shared__ int li[4 * KK];
    __shared__ float red[256];
    int b = blockIdx.y;
    int o = threadIdx.x & 63;
    int nn = threadIdx.x >> 6;
    int nbase = blockIdx.x * 128;
    float s = 0.f, ss = 0.f;

    for (int gidx = 0; gidx < 32; ++gidx) {
        int n0 = nbase + gidx * 4;
        __syncthreads();
        if (threadIdx.x < 4 * KK)
            li[threadIdx.x] = idxK[((size_t)b * NN + n0) * KK + threadIdx.x];
        __syncthreads();
        int n = n0 + nn;
        float y2v = y2[((size_t)b * NN + n) * 64 + o];
        float hm = -FLT_MAX, hn = FLT_MAX;
        for (int k = 0; k < KK; ++k) {
            int j = li[nn * KK + k];   // wave-uniform within a wave (nn fixed per wave)
            float h = y1[((size_t)b * NN + j) * 64 + o] + y2v;   // coalesced 256B row, L2-hot
            s += h;
            ss += h * h;
            hm = fmaxf(hm, h);
            hn = fminf(hn, h);
        }
        hmax[((size_t)b * NN + n) * 64 + o] = hm;
        hmin[((size_t)b * NN + n) * 64 + o] = hn;
    }

    __syncthreads();
    red[threadIdx.x] = s;
    __syncthreads();
    if (threadIdx.x < 64) {
        float v = red[o] + red[64 + o] + red[128 + o] + red[192 + o];
        atomicAdd(&stats[o], v);
    }
    __syncthreads();
    red[threadIdx.x] = ss;
    __syncthreads();
    if (threadIdx.x < 64) {
        float v = red[o] + red[64 + o] + red[128 + o] + red[192 + o];
        atomicAdd(&stats[64 + o], v);
    }
}

// ---------------- kernel C3: finalize BN + leaky + max-over-k ----------------
__global__ void kC3(const float* __restrict__ hmax, const float* __restrict__ hmin,
                    const float* __restrict__ stats, const float* __restrict__ gamma,
                    const float* __restrict__ beta, float* __restrict__ out) {
    int o = blockIdx.x;
    int b = blockIdx.y;
    const float cnt = (float)BB * NN * KK;
    float mean = stats[o] / cnt;
    float var = stats[64 + o] / cnt - mean * mean;
    float rs = rsqrtf(var + 1e-5f);
    float a = gamma[o] * rs;
    float b2 = beta[o] - a * mean;
    for (int n = threadIdx.x; n < NN; n += 256) {
        float hm = hmax[((size_t)b * NN + n) * 64 + o];
        float hn = hmin[((size_t)b * NN + n) * 64 + o];
        float hs = (a >= 0.f) ? hm : hn;   // affine monotone: pick max or min per sign
        float v = a * hs + b2;
        v = (v >= 0.f) ? v : 0.2f * v;
        out[((size_t)b * 64 + o) * NN + n] = v;   // coalesced
    }
}

extern "C" void kernel_launch(void* const* d_in, const int* in_sizes, int n_in,
                              void* d_out, int out_size, void* d_ws, size_t ws_size,
                              hipStream_t stream) {
    const float* x     = (const float*)d_in[0];
    const float* W     = (const float*)d_in[1];
    const float* gamma = (const float*)d_in[2];
    const float* beta  = (const float*)d_in[3];
    float* out = (float*)d_out;
    float* ws  = (float*)d_ws;

    float* xt    = ws + XT_OFF;
    float* sq    = ws + SQ_OFF;
    float* y1    = ws + Y1_OFF;
    float* y2    = ws + Y2_OFF;
    float* candd = ws + CD_OFF;
    int*   candi = (int*)(ws + CI_OFF);
    int*   idxK  = (int*)(ws + IX_OFF);
    float* hmax  = ws + HX_OFF;
    float* hmin  = ws + HN_OFF;
    float* stats = ws + ST_OFF;

    kA<<<dim3(NN / 64, BB), 64, 0, stream>>>(x, W, ws);
    kB<<<dim3(NN / 256, MS, BB), 256, 0, stream>>>(xt, sq, candd, candi);
    kM<<<dim3(BB * NN / 256), 256, 0, stream>>>(candd, candi, idxK);
    kC1<<<dim3(NN / 128, BB), 256, 0, stream>>>(y1, y2, idxK, hmax, hmin, stats);
    kC3<<<dim3(OO, BB), 256, 0, stream>>>(hmax, hmin, stats, gamma, beta, out);
}

// Round 3
// 572.633 us; speedup vs baseline: 2.2576x; 1.7797x over previous
//
#include <hip/hip_runtime.h>
#include <cfloat>

#define BB 2
#define NN 8192
#define OO 64
#define KK 20
#define MS 4          // point-splits in kernel B
#define CHUNK 2048    // points per split
#define QB 128        // queries per block (4 waves x 32)
#define CAP 20        // per-thread deferred candidate buffer depth

using f16x8  = __attribute__((ext_vector_type(8))) _Float16;
using f32x16 = __attribute__((ext_vector_type(16))) float;

// ws layout (float units)
#define XH_OFF ((size_t)0)                        // B*N*64 halves = B*N*32 floats
#define XL_OFF (XH_OFF + (size_t)BB*NN*32)
#define SQ_OFF (XL_OFF + (size_t)BB*NN*32)        // B*N
#define Y1_OFF (SQ_OFF + (size_t)BB*NN)           // B*N*64
#define Y2_OFF (Y1_OFF + (size_t)BB*NN*64)        // B*N*64
#define CD_OFF (Y2_OFF + (size_t)BB*NN*64)        // B*N*MS*K
#define CI_OFF (CD_OFF + (size_t)BB*NN*MS*KK)     // B*N*MS*K (int)
#define IX_OFF (CI_OFF + (size_t)BB*NN*MS*KK)     // B*N*K (int)
#define HX_OFF (IX_OFF + (size_t)BB*NN*KK)        // B*N*64
#define HN_OFF (HX_OFF + (size_t)BB*NN*64)        // B*N*64
#define ST_OFF (HN_OFF + (size_t)BB*NN*64)        // 128

// ---------------- kernel A: sq + fp16 hi/lo split + y1/y2 projections ----------------
__global__ void kA(const float* __restrict__ x, const float* __restrict__ W,
                   float* __restrict__ ws) {
    __shared__ float w1[4096];
    __shared__ float w2[4096];
    int b = blockIdx.y;
    int n = blockIdx.x * 256 + threadIdx.x;

    for (int i = threadIdx.x; i < 4096; i += 256) {
        int o = i >> 6, c = i & 63;
        float a  = W[o * 128 + c];
        float d  = W[o * 128 + 64 + c];
        w1[i] = a;
        w2[i] = d - a;
    }
    if (blockIdx.x == 0 && b == 0 && threadIdx.x < 128)
        ws[ST_OFF + threadIdx.x] = 0.f;   // zero stats accumulators (pre-kC1)
    __syncthreads();

    float xc[64];
    float sq = 0.f;
#pragma unroll
    for (int c = 0; c < 64; ++c) {
        float v = x[((size_t)b * 64 + c) * NN + n];   // coalesced across lanes
        xc[c] = v;
        sq += v * v;
    }
    ws[SQ_OFF + (size_t)b * NN + n] = sq;

    // fp16 split: x = hi + lo * 2^-11  (lo stored pre-scaled by 2048 -> stays normalized)
    _Float16* xh = (_Float16*)(ws + XH_OFF);
    _Float16* xl = (_Float16*)(ws + XL_OFF);
    size_t row = ((size_t)b * NN + n) * 64;
#pragma unroll
    for (int c8 = 0; c8 < 8; ++c8) {
        f16x8 vh, vl;
#pragma unroll
        for (int j = 0; j < 8; ++j) {
            float v = xc[c8 * 8 + j];
            _Float16 h = (_Float16)v;
            vh[j] = h;
            vl[j] = (_Float16)((v - (float)h) * 2048.f);
        }
        *(f16x8*)&xh[row + c8 * 8] = vh;
        *(f16x8*)&xl[row + c8 * 8] = vl;
    }

    float* y1r = ws + Y1_OFF + row;
    float* y2r = ws + Y2_OFF + row;
#pragma unroll 2
    for (int o = 0; o < 64; ++o) {
        float a1 = 0.f, a2 = 0.f;
#pragma unroll
        for (int c = 0; c < 64; ++c) {
            a1 += w1[o * 64 + c] * xc[c];
            a2 += w2[o * 64 + c] * xc[c];
        }
        y1r[o] = a1;
        y2r[o] = a2;
    }
}

// ---------------- kernel B: MFMA distances + in-register top-K ----------------
// Wave: 32 queries (B cols). A = point tile (32 rows). C: col=lane&31 (query),
// row = j + 8*r2 + 4*(lane>>5). Lane pair (L, L+32) covers disjoint point halves.
__global__ void __launch_bounds__(256, 1)
kB(const _Float16* __restrict__ xh, const _Float16* __restrict__ xl,
   const float* __restrict__ sq, float* __restrict__ candd, int* __restrict__ candi) {
    __shared__ unsigned long long buf[CAP * 256];
    const int tid  = threadIdx.x;
    const int lane = tid & 63;
    const int wv   = tid >> 6;
    const int qcol = lane & 31;
    const int kh   = lane >> 5;
    const int b      = blockIdx.z;
    const int qbase  = blockIdx.x * QB + wv * 32;
    const int pbase0 = blockIdx.y * CHUNK;

    f16x8 Qh[4], Ql[4];
    {
        size_t qr = ((size_t)b * NN + qbase + qcol) * 64 + kh * 8;
#pragma unroll
        for (int t = 0; t < 4; ++t) {
            Qh[t] = *(const f16x8*)&xh[qr + t * 16];
            Ql[t] = *(const f16x8*)&xl[qr + t * 16];
        }
    }

    float dk[KK];
    int   ik[KK];
#pragma unroll
    for (int i = 0; i < KK; ++i) { dk[i] = FLT_MAX; ik[i] = 0; }
    int cnt = 0;

    auto insert1 = [&](float d, int id) {
        dk[KK - 1] = d;
        ik[KK - 1] = id;
#pragma unroll
        for (int i = KK - 1; i > 0; --i) {
            float x0 = dk[i - 1], x1 = dk[i];
            bool sw = x1 < x0;              // strict <: earlier (lower idx) wins ties
            dk[i - 1] = sw ? x1 : x0;
            dk[i]     = sw ? x0 : x1;
            int y0 = ik[i - 1], y1v = ik[i];
            ik[i - 1] = sw ? y1v : y0;
            ik[i]     = sw ? y0 : y1v;
        }
    };

    auto flushbuf = [&]() {
#pragma unroll 1
        for (int j = 0; j < CAP; ++j) {
            if (!__any(j < cnt)) break;
            unsigned long long v = buf[j * 256 + tid];
            float d = __uint_as_float((unsigned)(v >> 32));
            int  id = (int)(unsigned)v;
            bool ins = (j < cnt) && (d < dk[KK - 1]);
            if (__any(ins)) {               // skip chain when all lanes stale
                if (ins) insert1(d, id);
            }
        }
        cnt = 0;
    };

    for (int pt = 0; pt < CHUNK; pt += 32) {
        const int pbase = pbase0 + pt;
        size_t pr = ((size_t)b * NN + pbase + qcol) * 64 + kh * 8;  // A row = lane&31

        f32x16 c0, c1;
#pragma unroll
        for (int i = 0; i < 16; ++i) { c0[i] = 0.f; c1[i] = 0.f; }
#pragma unroll
        for (int t = 0; t < 4; ++t) {
            f16x8 Ah = *(const f16x8*)&xh[pr + t * 16];
            f16x8 Al = *(const f16x8*)&xl[pr + t * 16];
            c0 = __builtin_amdgcn_mfma_f32_32x32x16_f16(Ah, Qh[t], c0, 0, 0, 0); // hi*hi
            c1 = __builtin_amdgcn_mfma_f32_32x32x16_f16(Ah, Ql[t], c1, 0, 0, 0); // hi*lo
            c1 = __builtin_amdgcn_mfma_f32_32x32x16_f16(Al, Qh[t], c1, 0, 0, 0); // lo*hi
        }

#pragma unroll
        for (int r2 = 0; r2 < 4; ++r2) {
            float4 sv = *(const float4*)&sq[(size_t)b * NN + pbase + 8 * r2 + 4 * kh];
            float svv[4] = {sv.x, sv.y, sv.z, sv.w};
#pragma unroll
            for (int j = 0; j < 4; ++j) {
                int i = r2 * 4 + j;
                float d = fmaf(-2.f, c0[i], svv[j]);          // d = sq[p] - 2*dot
                d = fmaf(-9.765625e-4f, c1[i], d);            // cross terms * 2^-11 * 2
                if (d < dk[KK - 1]) {
                    int id = pbase + j + 8 * r2 + 4 * kh;
                    buf[cnt * 256 + tid] =
                        ((unsigned long long)__float_as_uint(d) << 32) | (unsigned)id;
                    ++cnt;
                }
                if (__any(cnt >= CAP)) flushbuf();
            }
        }
    }
    flushbuf();

    // pair-merge: dump lists, lane kh==0 absorbs partner (same wave -> no barrier)
#pragma unroll
    for (int j = 0; j < KK; ++j)
        buf[j * 256 + tid] =
            ((unsigned long long)__float_as_uint(dk[j]) << 32) | (unsigned)ik[j];

    if (kh == 0) {
#pragma unroll 1
        for (int j = 0; j < KK; ++j) {
            unsigned long long v = buf[j * 256 + tid + 32];
            float d = __uint_as_float((unsigned)(v >> 32));
            int  id = (int)(unsigned)v;
            bool ins = d < dk[KK - 1];
            if (!__any(ins)) break;         // partner list sorted ascending
            if (ins) insert1(d, id);
        }
        int q = qbase + qcol;
        size_t base = (((size_t)b * NN + q) * MS + blockIdx.y) * KK;
#pragma unroll
        for (int i = 0; i < KK; ++i) {
            candd[base + i] = dk[i];
            candi[base + i] = ik[i];
        }
    }
}

// ---------------- kernel M: merge MS candidate lists per query ----------------
__global__ void kM(const float* __restrict__ candd, const int* __restrict__ candi,
                   int* __restrict__ idxK) {
    int g = blockIdx.x * 256 + threadIdx.x;   // 0 .. B*N-1
    const float* cd = &candd[(size_t)g * MS * KK];
    const int*   ci = &candi[(size_t)g * MS * KK];
    float dk[KK];
    int   ik[KK];
#pragma unroll
    for (int i = 0; i < KK; ++i) { dk[i] = cd[i]; ik[i] = ci[i]; }   // chunk 0, sorted
    for (int t = KK; t < MS * KK; ++t) {
        float d = cd[t];
        if (d < dk[KK - 1]) {   // ascending-m chunk order; strict < keeps earlier
            dk[KK - 1] = d;
            ik[KK - 1] = ci[t];
#pragma unroll
            for (int i = KK - 1; i > 0; --i) {
                float x0 = dk[i - 1], x1 = dk[i];
                bool sw = x1 < x0;
                dk[i - 1] = sw ? x1 : x0;
                dk[i]     = sw ? x0 : x1;
                int y0 = ik[i - 1], y1i = ik[i];
                ik[i - 1] = sw ? y1i : y0;
                ik[i]     = sw ? y0 : y1i;
            }
        }
    }
    int* outp = &idxK[(size_t)g * KK];
#pragma unroll
    for (int i = 0; i < KK; ++i) outp[i] = ik[i];
}

// ---------------- kernel C1: gather + stats + hmax/hmin ----------------
__global__ void kC1(const float* __restrict__ y1, const float* __restrict__ y2,
                    const int* __restrict__ idxK, float* __restrict__ hmax,
                    float* __restrict__ hmin, float* __restrict__ stats) {
    __shared__ int li[4 * KK];
    __shared__ float red[256];
    int b = blockIdx.y;
    int o = threadIdx.x & 63;
    int nn = threadIdx.x >> 6;
    int nbase = blockIdx.x * 128;
    float s = 0.f, ss = 0.f;

    for (int gidx = 0; gidx < 32; ++gidx) {
        int n0 = nbase + gidx * 4;
        __syncthreads();
        if (threadIdx.x < 4 * KK)
            li[threadIdx.x] = idxK[((size_t)b * NN + n0) * KK + threadIdx.x];
        __syncthreads();
        int n = n0 + nn;
        float y2v = y2[((size_t)b * NN + n) * 64 + o];
        float hm = -FLT_MAX, hn = FLT_MAX;
        for (int k = 0; k < KK; ++k) {
            int j = li[nn * KK + k];   // wave-uniform within a wave
            float h = y1[((size_t)b * NN + j) * 64 + o] + y2v;   // coalesced, L2-hot
            s += h;
            ss += h * h;
            hm = fmaxf(hm, h);
            hn = fminf(hn, h);
        }
        hmax[((size_t)b * NN + n) * 64 + o] = hm;
        hmin[((size_t)b * NN + n) * 64 + o] = hn;
    }

    __syncthreads();
    red[threadIdx.x] = s;
    __syncthreads();
    if (threadIdx.x < 64) {
        float v = red[o] + red[64 + o] + red[128 + o] + red[192 + o];
        atomicAdd(&stats[o], v);
    }
    __syncthreads();
    red[threadIdx.x] = ss;
    __syncthreads();
    if (threadIdx.x < 64) {
        float v = red[o] + red[64 + o] + red[128 + o] + red[192 + o];
        atomicAdd(&stats[64 + o], v);
    }
}

// ---------------- kernel C3: finalize BN + leaky + max-over-k ----------------
__global__ void kC3(const float* __restrict__ hmax, const float* __restrict__ hmin,
                    const float* __restrict__ stats, const float* __restrict__ gamma,
                    const float* __restrict__ beta, float* __restrict__ out) {
    int o = blockIdx.x;
    int b = blockIdx.y;
    const float cnt = (float)BB * NN * KK;
    float mean = stats[o] / cnt;
    float var = stats[64 + o] / cnt - mean * mean;
    float rs = rsqrtf(var + 1e-5f);
    float a = gamma[o] * rs;
    float b2 = beta[o] - a * mean;
    for (int n = threadIdx.x; n < NN; n += 256) {
        float hm = hmax[((size_t)b * NN + n) * 64 + o];
        float hn = hmin[((size_t)b * NN + n) * 64 + o];
        float hs = (a >= 0.f) ? hm : hn;   // affine monotone: max or min per sign of a
        float v = a * hs + b2;
        v = (v >= 0.f) ? v : 0.2f * v;
        out[((size_t)b * 64 + o) * NN + n] = v;   // coalesced
    }
}

extern "C" void kernel_launch(void* const* d_in, const int* in_sizes, int n_in,
                              void* d_out, int out_size, void* d_ws, size_t ws_size,
                              hipStream_t stream) {
    const float* x     = (const float*)d_in[0];
    const float* W     = (const float*)d_in[1];
    const float* gamma = (const float*)d_in[2];
    const float* beta  = (const float*)d_in[3];
    float* out = (float*)d_out;
    float* ws  = (float*)d_ws;

    _Float16* xh = (_Float16*)(ws + XH_OFF);
    _Float16* xl = (_Float16*)(ws + XL_OFF);
    float* sq    = ws + SQ_OFF;
    float* y1    = ws + Y1_OFF;
    float* y2    = ws + Y2_OFF;
    float* candd = ws + CD_OFF;
    int*   candi = (int*)(ws + CI_OFF);
    int*   idxK  = (int*)(ws + IX_OFF);
    float* hmax  = ws + HX_OFF;
    float* hmin  = ws + HN_OFF;
    float* stats = ws + ST_OFF;

    kA<<<dim3(NN / 256, BB), 256, 0, stream>>>(x, W, ws);
    kB<<<dim3(NN / QB, MS, BB), 256, 0, stream>>>(xh, xl, sq, candd, candi);
    kM<<<dim3(BB * NN / 256), 256, 0, stream>>>(candd, candi, idxK);
    kC1<<<dim3(NN / 128, BB), 256, 0, stream>>>(y1, y2, idxK, hmax, hmin, stats);
    kC3<<<dim3(OO, BB), 256, 0, stream>>>(hmax, hmin, stats, gamma, beta, out);
}